// Round 1
// 586.509 us; speedup vs baseline: 1.0298x; 1.0298x over previous
//
#include <hip/hip_runtime.h>

#define BB   4
#define SS   2048
#define HH   16
#define DM   1024
#define DKV  64
#define LNEPS 1e-6f

#define MD_BF16 0
#define MD_F32  1
#define MD_F16  2

typedef __attribute__((ext_vector_type(8))) short bf16x8;
typedef __attribute__((ext_vector_type(4))) float f32x4;
#define MFMA16(a,b,c) __builtin_amdgcn_mfma_f32_16x16x32_bf16(a,b,c,0,0,0)

// ---------- dtype helpers ----------
__device__ __forceinline__ float2 unpack2(unsigned int u) {
    union { unsigned int i; float f; } a, b;
    a.i = u << 16;
    b.i = u & 0xffff0000u;
    return make_float2(a.f, b.f);
}
__device__ __forceinline__ unsigned short f2bf(float f) {   // RNE
    union { float f; unsigned int i; } c; c.f = f;
    unsigned int u = c.i;
    unsigned int r = u + 0x7fffu + ((u >> 16) & 1u);
    return (unsigned short)(r >> 16);
}
__device__ __forceinline__ unsigned short f2bf_t(float f) { // truncate
    union { float f; unsigned int i; } c; c.f = f;
    return (unsigned short)(c.i >> 16);
}
__device__ __forceinline__ float h2f(unsigned int bits16) {
    unsigned short s = (unsigned short)bits16;
    _Float16 x;
    __builtin_memcpy(&x, &s, 2);
    return (float)x;
}
__device__ __forceinline__ void load8m(const void* p, int mode, size_t e0, float* o) {
    if (mode == MD_F32) {
        const float* f = (const float*)p + e0;
        float4 a = *(const float4*)f;
        float4 b = *(const float4*)(f + 4);
        o[0] = a.x; o[1] = a.y; o[2] = a.z; o[3] = a.w;
        o[4] = b.x; o[5] = b.y; o[6] = b.z; o[7] = b.w;
    } else {
        uint4 u = *(const uint4*)((const ushort*)p + e0);
        unsigned v[4] = {u.x, u.y, u.z, u.w};
        if (mode == MD_BF16) {
#pragma unroll
            for (int j = 0; j < 4; ++j) { float2 t = unpack2(v[j]); o[2*j] = t.x; o[2*j+1] = t.y; }
        } else {
#pragma unroll
            for (int j = 0; j < 4; ++j) { o[2*j] = h2f(v[j] & 0xFFFFu); o[2*j+1] = h2f(v[j] >> 16); }
        }
    }
}
__device__ __forceinline__ void load4m(const void* p, int mode, size_t e0, float* o) {
    if (mode == MD_F32) {
        float4 v = *(const float4*)((const float*)p + e0);
        o[0] = v.x; o[1] = v.y; o[2] = v.z; o[3] = v.w;
    } else {
        uint2 u = *(const uint2*)((const ushort*)p + e0);
        if (mode == MD_BF16) {
            float2 a = unpack2(u.x), b = unpack2(u.y);
            o[0] = a.x; o[1] = a.y; o[2] = b.x; o[3] = b.y;
        } else {
            o[0] = h2f(u.x & 0xFFFFu); o[1] = h2f(u.x >> 16);
            o[2] = h2f(u.y & 0xFFFFu); o[3] = h2f(u.y >> 16);
        }
    }
}
__device__ __forceinline__ float loadS(const void* p, int mode, size_t i) {
    if (mode == MD_F32) return ((const float*)p)[i];
    unsigned short u = ((const ushort*)p)[i];
    if (mode == MD_BF16) { union { unsigned i; float f; } c; c.i = (unsigned)u << 16; return c.f; }
    return h2f(u);
}

// =====================================================================
// Fused dtype sniff: one block per float tensor.
// =====================================================================
struct SniffArgs { const void* p[10]; int nhalf[10]; };

__global__ void sniff_all(SniffArgs a, int* __restrict__ modes) {
    __shared__ int cE, cO;
    const int slots[9] = {0, 1, 2, 4, 5, 6, 7, 8, 9};
    const int slot = slots[blockIdx.x];
    const ushort* p = (const ushort*)a.p[slot];
    const int nhalf = a.nhalf[slot];
    if (threadIdx.x == 0) { cE = 0; cO = 0; }
    __syncthreads();
    int e = 0, o = 0;
    for (int i = threadIdx.x; i < nhalf; i += 256) {
        unsigned ex = (p[i] >> 7) & 0xFFu;
        int hit = (ex < 100u || ex == 0xFFu) ? 1 : 0;
        if (i & 1) o += hit; else e += hit;
    }
    atomicAdd(&cE, e);
    atomicAdd(&cO, o);
    __syncthreads();
    if (threadIdx.x == 0) {
        int total = cE + cO;
        modes[slot] = (total < 48) ? MD_BF16 : ((cO * 4 < cE) ? MD_F32 : MD_F16);
    }
}

// =====================================================================
// Mask bit-pack: mask[B][S][S] int32 -> pm bitmask (1 bit per element),
// 32 cols per uint32 word.  2 MB total, L2-resident during attention.
// Each thread produces one word from 32 consecutive ints (8x int4 loads,
// 128B contiguous per thread).  Grid: 524288/256 = 2048 blocks.
// =====================================================================
__global__ __launch_bounds__(256) void mpack(
    const int* __restrict__ mask, unsigned int* __restrict__ pm)
{
    const int w = blockIdx.x * 256 + threadIdx.x;
    const int* p = mask + (size_t)w * 32;
    unsigned int bits = 0u;
#pragma unroll
    for (int j = 0; j < 8; ++j) {
        int4 v = *(const int4*)(p + j * 4);
        bits |= (v.x ? 1u : 0u) << (4 * j);
        bits |= (v.y ? 1u : 0u) << (4 * j + 1);
        bits |= (v.z ? 1u : 0u) << (4 * j + 2);
        bits |= (v.w ? 1u : 0u) << (4 * j + 3);
    }
    pm[w] = bits;
}

// =====================================================================
// Weight transpose + bf16 convert: W[k][n] (any dtype) -> Wt[n][k] bf16.
// 64x64 tiles, grid (16,16).
// =====================================================================
__global__ __launch_bounds__(256) void wtrans(
    const void* __restrict__ W, ushort* __restrict__ Wt,
    const int* __restrict__ modes, int wslot)
{
    __shared__ ushort T[64][68];
    const int tid = threadIdx.x;
    const int m = modes[wslot];
    const int k0 = blockIdx.y * 64, n0 = blockIdx.x * 64;

    const int r = tid >> 2, c = (tid & 3) * 16;
    float t[4];
#pragma unroll
    for (int j = 0; j < 4; ++j) {
        load4m(W, m, (size_t)(k0 + r) * DM + n0 + c + 4 * j, t);
#pragma unroll
        for (int i = 0; i < 4; ++i) T[r][c + 4 * j + i] = f2bf(t[i]);
    }
    __syncthreads();

    const int rn = tid >> 2, ck = (tid & 3) * 16;
    union { ushort u[8]; uint4 v; } p0, p1;
#pragma unroll
    for (int j = 0; j < 8; ++j) { p0.u[j] = T[ck + j][rn]; p1.u[j] = T[ck + 8 + j][rn]; }
    ushort* op = &Wt[(size_t)(n0 + rn) * DM + k0 + ck];
    *(uint4*)op = p0.v;
    *(uint4*)(op + 8) = p1.v;
}

// =====================================================================
// MFMA projection GEMM: A[8192,1024] (sniffed dtype) @ Wt[n][k] bf16
// -> bf16 out.  128x128 tile, BK=32, 4 waves x (4x4) 16x16x32 MFMA.
// scale folded into epilogue (0.125 for Q).
// vmode 0: out[b][h][s][d]; vmode 1: out[b][h][d][s] (V transposed).
// =====================================================================
__global__ __launch_bounds__(256) void proj_mfma(
    const void* __restrict__ Araw, const ushort* __restrict__ Wt,
    ushort* __restrict__ Out, const int* __restrict__ modes,
    int aslot, int vmode, float scale)
{
    __shared__ __align__(16) ushort As[128][40];
    __shared__ __align__(16) ushort Bs[128][40];

    const int tid = threadIdx.x;
    const int lane = tid & 63, wv = tid >> 6;
    const int quad = lane >> 4, L = lane & 15;
    const int m0 = blockIdx.y * 128, n0 = blockIdx.x * 128;
    const int wm = (wv >> 1) * 64, wn = (wv & 1) * 64;
    const int ma = modes[aslot];

    f32x4 acc[4][4];
#pragma unroll
    for (int i = 0; i < 4; ++i)
#pragma unroll
        for (int j = 0; j < 4; ++j) { acc[i][j][0] = 0.f; acc[i][j][1] = 0.f; acc[i][j][2] = 0.f; acc[i][j][3] = 0.f; }

    const int arow = tid >> 1, aseg = tid & 1;

    for (int kt = 0; kt < 32; ++kt) {
        const int k0 = kt * 32;
        {
            float t0[8], t1[8];
            load8m(Araw, ma, (size_t)(m0 + arow) * DM + k0 + aseg * 16, t0);
            load8m(Araw, ma, (size_t)(m0 + arow) * DM + k0 + aseg * 16 + 8, t1);
            union { ushort u[8]; uint4 v; } p0, p1;
#pragma unroll
            for (int j = 0; j < 8; ++j) { p0.u[j] = f2bf(t0[j]); p1.u[j] = f2bf(t1[j]); }
            *(uint4*)&As[arow][aseg * 16]     = p0.v;
            *(uint4*)&As[arow][aseg * 16 + 8] = p1.v;

            const ushort* wp = &Wt[(size_t)(n0 + arow) * DM + k0 + aseg * 16];
            *(uint4*)&Bs[arow][aseg * 16]     = *(const uint4*)wp;
            *(uint4*)&Bs[arow][aseg * 16 + 8] = *(const uint4*)(wp + 8);
        }
        __syncthreads();

        bf16x8 af[4], bfr[4];
#pragma unroll
        for (int tm = 0; tm < 4; ++tm) af[tm] = *(const bf16x8*)&As[wm + tm * 16 + L][quad * 8];
#pragma unroll
        for (int tn = 0; tn < 4; ++tn) bfr[tn] = *(const bf16x8*)&Bs[wn + tn * 16 + L][quad * 8];
#pragma unroll
        for (int tm = 0; tm < 4; ++tm)
#pragma unroll
            for (int tn = 0; tn < 4; ++tn)
                acc[tm][tn] = MFMA16(af[tm], bfr[tn], acc[tm][tn]);
        __syncthreads();
    }

#pragma unroll
    for (int tm = 0; tm < 4; ++tm)
#pragma unroll
        for (int tn = 0; tn < 4; ++tn)
#pragma unroll
            for (int r = 0; r < 4; ++r) {
                const int mm = m0 + wm + tm * 16 + quad * 4 + r;
                const int n = n0 + wn + tn * 16 + L;
                const int b = mm >> 11, s = mm & 2047;
                const int h = n >> 6, d = n & 63;
                const size_t o = vmode
                    ? ((size_t)(b * HH + h) * DKV + d) * SS + s
                    : ((size_t)(b * HH + h) * SS + s) * DKV + d;
                Out[o] = f2bf(acc[tm][tn][r] * scale);
            }
}

// =====================================================================
// MFMA flash attention, fixed-base softmax (no running max; scores are
// bounded since Q was pre-scaled by 1/8 at projection).
// Q/K [bh][s][64] bf16 (Q pre-scaled), V transposed [bh][d][s] bf16.
// Mask consumed as packed bitmask pm[b][q][k>>5] (2 MB, L2-resident).
// Grid (qtile, bh): resident blocks share heads -> KV stays in L2.
// Block: 64 q-rows, 4 waves; K-tiles of 64.  Q A-fragments hoisted to
// registers (no Q LDS).  l deferred to one end-reduction.
// =====================================================================
__global__ __launch_bounds__(256) void attn_mfma(
    const ushort* __restrict__ Q, const ushort* __restrict__ K,
    const ushort* __restrict__ Vt, const unsigned int* __restrict__ pm,
    ushort* __restrict__ Xo)
{
    __shared__ __align__(16) ushort Ks[64][72];
    __shared__ __align__(16) ushort Vs[64][72];
    __shared__ __align__(16) ushort Ps[64][72];

    const int tid = threadIdx.x;
    const int lane = tid & 63, wv = tid >> 6;
    const int quad = lane >> 4, L = lane & 15;
    const int bh = blockIdx.y, b = bh >> 4, h = bh & 15;
    const int q0 = blockIdx.x * 64;

    // hoisted Q A-fragments (row = q0+wv*16+L, k = quad*8.. / 32+quad*8..)
    const ushort* qp = &Q[((size_t)bh * SS + q0 + wv * 16 + L) * DKV + quad * 8];
    const bf16x8 aq0 = *(const bf16x8*)qp;
    const bf16x8 aq1 = *(const bf16x8*)(qp + 32);

    f32x4 O[4];
    float lacc[4];
#pragma unroll
    for (int t = 0; t < 4; ++t) { O[t][0] = 0.f; O[t][1] = 0.f; O[t][2] = 0.f; O[t][3] = 0.f; }
#pragma unroll
    for (int r = 0; r < 4; ++r) lacc[r] = 0.f;

    const int sr = tid >> 2, sg = tid & 3;
    const ushort* kbase = &K[((size_t)bh * SS + sr) * DKV + sg * 16];
    const ushort* vbase = &Vt[((size_t)bh * DKV + sr) * SS + sg * 16];
    // packed-mask row pointers: 64 words per q-row
    const unsigned int* pmr[4];
#pragma unroll
    for (int r = 0; r < 4; ++r)
        pmr[r] = pm + ((size_t)b * SS + q0 + wv * 16 + quad * 4 + r) * 64;

    for (int kt = 0; kt < 32; ++kt) {
        __syncthreads();   // prior tile's frag reads done before restaging
        *(uint4*)&Ks[sr][sg * 16]     = *(const uint4*)kbase;
        *(uint4*)&Ks[sr][sg * 16 + 8] = *(const uint4*)(kbase + 8);
        *(uint4*)&Vs[sr][sg * 16]     = *(const uint4*)vbase;
        *(uint4*)&Vs[sr][sg * 16 + 8] = *(const uint4*)(vbase + 8);
        kbase += 64 * DKV;
        vbase += 64;

        // mask words for this 64-col tile (issued early to hide latency)
        uint2 mw[4];
#pragma unroll
        for (int r = 0; r < 4; ++r) mw[r] = *(const uint2*)(pmr[r] + 2 * kt);

        __syncthreads();

        // ---- QK^T (scores already scaled via Q) ----
        f32x4 sc[4];
#pragma unroll
        for (int t = 0; t < 4; ++t) {
            bf16x8 b0 = *(const bf16x8*)&Ks[t * 16 + L][quad * 8];
            bf16x8 b1 = *(const bf16x8*)&Ks[t * 16 + L][32 + quad * 8];
            f32x4 c; c[0] = 0.f; c[1] = 0.f; c[2] = 0.f; c[3] = 0.f;
            c = MFMA16(aq0, b0, c);
            c = MFMA16(aq1, b1, c);
            sc[t] = c;
        }

        // ---- fixed-base masked softmax (bit-test, no global loads) ----
#pragma unroll
        for (int r = 0; r < 4; ++r) {
            const unsigned mx = mw[r].x, my = mw[r].y;
#pragma unroll
            for (int t = 0; t < 4; ++t) {
                const float s = fminf(sc[t][r], 30.f);
                const float e = __expf(s);
                const unsigned wsel = (t & 2) ? my : mx;
                const float p = ((wsel >> ((t & 1) * 16 + L)) & 1u) ? e : 0.f;
                lacc[r] += p;
                Ps[wv * 16 + quad * 4 + r][t * 16 + L] = f2bf_t(p);
            }
        }

        // ---- PV (same-wave LDS dependency; no barrier needed) ----
        bf16x8 ap0 = *(const bf16x8*)&Ps[wv * 16 + L][quad * 8];
        bf16x8 ap1 = *(const bf16x8*)&Ps[wv * 16 + L][32 + quad * 8];
#pragma unroll
        for (int t = 0; t < 4; ++t) {
            bf16x8 v0 = *(const bf16x8*)&Vs[t * 16 + L][quad * 8];
            bf16x8 v1 = *(const bf16x8*)&Vs[t * 16 + L][32 + quad * 8];
            O[t] = MFMA16(ap0, v0, O[t]);
            O[t] = MFMA16(ap1, v1, O[t]);
        }
    }

    // final l reduction over the 16 lanes of each quad, then write X
    float inv[4];
#pragma unroll
    for (int r = 0; r < 4; ++r) {
        float l = lacc[r];
#pragma unroll
        for (int off = 1; off < 16; off <<= 1) l += __shfl_xor(l, off, 64);
        inv[r] = 1.f / l;
    }
#pragma unroll
    for (int t = 0; t < 4; ++t)
#pragma unroll
        for (int r = 0; r < 4; ++r) {
            const int qg = q0 + wv * 16 + quad * 4 + r;
            Xo[((size_t)b * SS + qg) * DM + h * DKV + t * 16 + L] = f2bf(O[t][r] * inv[r]);
        }
}

// =====================================================================
// MFMA output projection: X(bf16) @ Wt_out(bf16,[n][k]) + query -> fp32.
// =====================================================================
__global__ __launch_bounds__(256) void oproj_mfma(
    const ushort* __restrict__ Xin, const ushort* __restrict__ Wt,
    const void* __restrict__ Qres, float* __restrict__ Out,
    const int* __restrict__ modes)
{
    __shared__ __align__(16) ushort As[128][40];
    __shared__ __align__(16) ushort Bs[128][40];

    const int tid = threadIdx.x;
    const int lane = tid & 63, wv = tid >> 6;
    const int quad = lane >> 4, L = lane & 15;
    const int m0 = blockIdx.y * 128, n0 = blockIdx.x * 128;
    const int wm = (wv >> 1) * 64, wn = (wv & 1) * 64;
    const int mq = modes[0];

    f32x4 acc[4][4];
#pragma unroll
    for (int i = 0; i < 4; ++i)
#pragma unroll
        for (int j = 0; j < 4; ++j) { acc[i][j][0] = 0.f; acc[i][j][1] = 0.f; acc[i][j][2] = 0.f; acc[i][j][3] = 0.f; }

    const int arow = tid >> 1, aseg = tid & 1;

    for (int kt = 0; kt < 32; ++kt) {
        const int k0 = kt * 32;
        {
            const ushort* xp = &Xin[(size_t)(m0 + arow) * DM + k0 + aseg * 16];
            *(uint4*)&As[arow][aseg * 16]     = *(const uint4*)xp;
            *(uint4*)&As[arow][aseg * 16 + 8] = *(const uint4*)(xp + 8);
            const ushort* wp = &Wt[(size_t)(n0 + arow) * DM + k0 + aseg * 16];
            *(uint4*)&Bs[arow][aseg * 16]     = *(const uint4*)wp;
            *(uint4*)&Bs[arow][aseg * 16 + 8] = *(const uint4*)(wp + 8);
        }
        __syncthreads();

        bf16x8 af[4], bfr[4];
#pragma unroll
        for (int tm = 0; tm < 4; ++tm) af[tm] = *(const bf16x8*)&As[wm + tm * 16 + L][quad * 8];
#pragma unroll
        for (int tn = 0; tn < 4; ++tn) bfr[tn] = *(const bf16x8*)&Bs[wn + tn * 16 + L][quad * 8];
#pragma unroll
        for (int tm = 0; tm < 4; ++tm)
#pragma unroll
            for (int tn = 0; tn < 4; ++tn)
                acc[tm][tn] = MFMA16(af[tm], bfr[tn], acc[tm][tn]);
        __syncthreads();
    }

#pragma unroll
    for (int tm = 0; tm < 4; ++tm)
#pragma unroll
        for (int tn = 0; tn < 4; ++tn)
#pragma unroll
            for (int r = 0; r < 4; ++r) {
                const int mm = m0 + wm + tm * 16 + quad * 4 + r;
                const int n = n0 + wn + tn * 16 + L;
                const size_t idx = (size_t)mm * DM + n;
                Out[idx] = acc[tm][tn][r] + loadS(Qres, mq, idx);
            }
}

// =====================================================================
// In-place LayerNorm over d_out rows (8192 x 1024 fp32), 1 row per wave.
// =====================================================================
__global__ __launch_bounds__(256) void ln_k(
    float* __restrict__ Out, const void* __restrict__ G,
    const void* __restrict__ Bt, const int* __restrict__ modes)
{
    const int tid = threadIdx.x, wv = tid >> 6, lane = tid & 63;
    const int row = blockIdx.x * 4 + wv;
    const int mg = modes[8], mb = modes[9];
    const size_t base = (size_t)row * DM + lane * 16;

    float v[16];
    float s = 0.f, q = 0.f;
#pragma unroll
    for (int j = 0; j < 16; j += 4) {
        float4 t = *(const float4*)&Out[base + j];
        v[j] = t.x; v[j+1] = t.y; v[j+2] = t.z; v[j+3] = t.w;
        s += t.x + t.y + t.z + t.w;
        q += t.x*t.x + t.y*t.y + t.z*t.z + t.w*t.w;
    }
#pragma unroll
    for (int off = 1; off < 64; off <<= 1) {
        s += __shfl_xor(s, off, 64);
        q += __shfl_xor(q, off, 64);
    }
    const float mu = s * (1.f / 1024.f);
    const float var = q * (1.f / 1024.f) - mu * mu;
    const float inv = rsqrtf(var + LNEPS);

    float gj[16], bj[16];
#pragma unroll
    for (int j = 0; j < 16; j += 4) {
        load4m(G,  mg, (size_t)lane * 16 + j, gj + j);
        load4m(Bt, mb, (size_t)lane * 16 + j, bj + j);
    }
#pragma unroll
    for (int j = 0; j < 16; j += 4) {
        float4 o;
        o.x = (v[j]   - mu) * inv * gj[j]   + bj[j];
        o.y = (v[j+1] - mu) * inv * gj[j+1] + bj[j+1];
        o.z = (v[j+2] - mu) * inv * gj[j+2] + bj[j+2];
        o.w = (v[j+3] - mu) * inv * gj[j+3] + bj[j+3];
        *(float4*)&Out[base + j] = o;
    }
}

// =====================================================================
extern "C" void kernel_launch(void* const* d_in, const int* in_sizes, int n_in,
                              void* d_out, int out_size, void* d_ws, size_t ws_size,
                              hipStream_t stream)
{
    const void* query = d_in[0];
    const void* key_i = d_in[1];
    const void* value = d_in[2];
    const int*  mask  = (const int*)d_in[3];
    const void* w_qs  = d_in[4];
    const void* w_ks  = d_in[5];
    const void* w_vs  = d_in[6];
    const void* w_out = d_in[7];
    const void* ln_g  = d_in[8];
    const void* ln_b  = d_in[9];
    float* out = (float*)d_out;

    // ws layout (proven 64MB+256B budget):
    // [modes 256B][Qw 16MB][Kw 16MB][Vw 16MB][Xw 16MB]
    // Wt for proj weights aliases the (not-yet-written) Xw region;
    // Wt for w_out aliases the (dead-after-attn) Qw region.
    // Packed mask (2MB) lives in d_out, which is dead until oproj_mfma
    // overwrites it entirely.
    int* modes = (int*)d_ws;
    const size_t PE = (size_t)BB * HH * SS * DKV;  // 8,388,608
    ushort* Qw = (ushort*)((char*)d_ws + 256);
    ushort* Kw = Qw + PE;
    ushort* Vw = Kw + PE;   // transposed layout [bh][d][s]
    ushort* Xw = Vw + PE;
    ushort* Wt  = Xw;       // 2MB scratch, used only before attn
    ushort* Wt2 = Qw;       // 2MB scratch for w_out, used after attn
    unsigned int* pmask = (unsigned int*)d_out;  // 2MB packed mask scratch

    SniffArgs sa;
    for (int i = 0; i < 10; ++i) {
        sa.p[i] = d_in[i];
        sa.nhalf[i] = in_sizes[i] < 4096 ? in_sizes[i] : 4096;
    }
    sniff_all<<<9, 256, 0, stream>>>(sa, modes);
    mpack<<<2048, 256, 0, stream>>>(mask, pmask);

    dim3 gproj(8, 64), gtr(16, 16);

    wtrans<<<gtr, 256, 0, stream>>>(w_qs, Wt, modes, 4);
    proj_mfma<<<gproj, 256, 0, stream>>>(query, Wt, Qw, modes, 0, 0, 0.125f);
    wtrans<<<gtr, 256, 0, stream>>>(w_ks, Wt, modes, 5);
    proj_mfma<<<gproj, 256, 0, stream>>>(key_i, Wt, Kw, modes, 1, 0, 1.0f);
    wtrans<<<gtr, 256, 0, stream>>>(w_vs, Wt, modes, 6);
    proj_mfma<<<gproj, 256, 0, stream>>>(value, Wt, Vw, modes, 2, 1, 1.0f);

    attn_mfma<<<dim3(32, 64), 256, 0, stream>>>(Qw, Kw, Vw, pmask, Xw);

    wtrans<<<gtr, 256, 0, stream>>>(w_out, Wt2, modes, 7);
    oproj_mfma<<<gproj, 256, 0, stream>>>(Xw, Wt2, query, out, modes);
    ln_k<<<2048, 256, 0, stream>>>(out, ln_g, ln_b, modes);
}

// Round 2
// 536.364 us; speedup vs baseline: 1.1261x; 1.0935x over previous
//
#include <hip/hip_runtime.h>

#define BB   4
#define SS   2048
#define HH   16
#define DM   1024
#define DKV  64
#define LNEPS 1e-6f

#define MD_BF16 0
#define MD_F32  1
#define MD_F16  2

typedef __attribute__((ext_vector_type(8))) short bf16x8;
typedef __attribute__((ext_vector_type(4))) float f32x4;
#define MFMA16(a,b,c) __builtin_amdgcn_mfma_f32_16x16x32_bf16(a,b,c,0,0,0)

// async global->LDS DMA, 16B per lane (dest = wave-uniform base + lane*16)
__device__ __forceinline__ void gl_lds16(const ushort* g, ushort* l) {
    __builtin_amdgcn_global_load_lds(
        (const __attribute__((address_space(1))) void*)g,
        (__attribute__((address_space(3))) void*)l, 16, 0, 0);
}

// ---------- dtype helpers ----------
__device__ __forceinline__ float2 unpack2(unsigned int u) {
    union { unsigned int i; float f; } a, b;
    a.i = u << 16;
    b.i = u & 0xffff0000u;
    return make_float2(a.f, b.f);
}
__device__ __forceinline__ unsigned short f2bf(float f) {   // RNE
    union { float f; unsigned int i; } c; c.f = f;
    unsigned int u = c.i;
    unsigned int r = u + 0x7fffu + ((u >> 16) & 1u);
    return (unsigned short)(r >> 16);
}
__device__ __forceinline__ unsigned short f2bf_t(float f) { // truncate
    union { float f; unsigned int i; } c; c.f = f;
    return (unsigned short)(c.i >> 16);
}
__device__ __forceinline__ float h2f(unsigned int bits16) {
    unsigned short s = (unsigned short)bits16;
    _Float16 x;
    __builtin_memcpy(&x, &s, 2);
    return (float)x;
}
__device__ __forceinline__ void load8m(const void* p, int mode, size_t e0, float* o) {
    if (mode == MD_F32) {
        const float* f = (const float*)p + e0;
        float4 a = *(const float4*)f;
        float4 b = *(const float4*)(f + 4);
        o[0] = a.x; o[1] = a.y; o[2] = a.z; o[3] = a.w;
        o[4] = b.x; o[5] = b.y; o[6] = b.z; o[7] = b.w;
    } else {
        uint4 u = *(const uint4*)((const ushort*)p + e0);
        unsigned v[4] = {u.x, u.y, u.z, u.w};
        if (mode == MD_BF16) {
#pragma unroll
            for (int j = 0; j < 4; ++j) { float2 t = unpack2(v[j]); o[2*j] = t.x; o[2*j+1] = t.y; }
        } else {
#pragma unroll
            for (int j = 0; j < 4; ++j) { o[2*j] = h2f(v[j] & 0xFFFFu); o[2*j+1] = h2f(v[j] >> 16); }
        }
    }
}
__device__ __forceinline__ void load4m(const void* p, int mode, size_t e0, float* o) {
    if (mode == MD_F32) {
        float4 v = *(const float4*)((const float*)p + e0);
        o[0] = v.x; o[1] = v.y; o[2] = v.z; o[3] = v.w;
    } else {
        uint2 u = *(const uint2*)((const ushort*)p + e0);
        if (mode == MD_BF16) {
            float2 a = unpack2(u.x), b = unpack2(u.y);
            o[0] = a.x; o[1] = a.y; o[2] = b.x; o[3] = b.y;
        } else {
            o[0] = h2f(u.x & 0xFFFFu); o[1] = h2f(u.x >> 16);
            o[2] = h2f(u.y & 0xFFFFu); o[3] = h2f(u.y >> 16);
        }
    }
}
__device__ __forceinline__ float loadS(const void* p, int mode, size_t i) {
    if (mode == MD_F32) return ((const float*)p)[i];
    unsigned short u = ((const ushort*)p)[i];
    if (mode == MD_BF16) { union { unsigned i; float f; } c; c.i = (unsigned)u << 16; return c.f; }
    return h2f(u);
}

// =====================================================================
// Fused dtype sniff: one block per float tensor.
// =====================================================================
struct SniffArgs { const void* p[10]; int nhalf[10]; };

__global__ void sniff_all(SniffArgs a, int* __restrict__ modes) {
    __shared__ int cE, cO;
    const int slots[9] = {0, 1, 2, 4, 5, 6, 7, 8, 9};
    const int slot = slots[blockIdx.x];
    const ushort* p = (const ushort*)a.p[slot];
    const int nhalf = a.nhalf[slot];
    if (threadIdx.x == 0) { cE = 0; cO = 0; }
    __syncthreads();
    int e = 0, o = 0;
    for (int i = threadIdx.x; i < nhalf; i += 256) {
        unsigned ex = (p[i] >> 7) & 0xFFu;
        int hit = (ex < 100u || ex == 0xFFu) ? 1 : 0;
        if (i & 1) o += hit; else e += hit;
    }
    atomicAdd(&cE, e);
    atomicAdd(&cO, o);
    __syncthreads();
    if (threadIdx.x == 0) {
        int total = cE + cO;
        modes[slot] = (total < 48) ? MD_BF16 : ((cO * 4 < cE) ? MD_F32 : MD_F16);
    }
}

// =====================================================================
// Mask bit-pack: mask[B][S][S] int32 -> 1 bit/elem (2 MB, L2-resident).
// =====================================================================
__global__ __launch_bounds__(256) void mpack(
    const int* __restrict__ mask, unsigned int* __restrict__ pm)
{
    const int w = blockIdx.x * 256 + threadIdx.x;
    const int* p = mask + (size_t)w * 32;
    unsigned int bits = 0u;
#pragma unroll
    for (int j = 0; j < 8; ++j) {
        int4 v = *(const int4*)(p + j * 4);
        bits |= (v.x ? 1u : 0u) << (4 * j);
        bits |= (v.y ? 1u : 0u) << (4 * j + 1);
        bits |= (v.z ? 1u : 0u) << (4 * j + 2);
        bits |= (v.w ? 1u : 0u) << (4 * j + 3);
    }
    pm[w] = bits;
}

// =====================================================================
// A-convert: any sniffed dtype -> bf16, 16 elems/thread. grid 2048x256.
// Single f2bf rounding — numerically identical to the old in-GEMM path.
// =====================================================================
__global__ __launch_bounds__(256) void aconv(
    const void* __restrict__ A, ushort* __restrict__ Ab,
    const int* __restrict__ modes, int slot)
{
    const int m = modes[slot];
    const size_t e0 = ((size_t)blockIdx.x * 256 + threadIdx.x) * 16;
    float t[16];
    load8m(A, m, e0, t);
    load8m(A, m, e0 + 8, t + 8);
    union { ushort u[16]; uint4 v[2]; } p;
#pragma unroll
    for (int j = 0; j < 16; ++j) p.u[j] = f2bf(t[j]);
    *(uint4*)&Ab[e0]     = p.v[0];
    *(uint4*)&Ab[e0 + 8] = p.v[1];
}

// =====================================================================
// Weight transpose + bf16 convert: W[k][n] (any dtype) -> Wt[n][k] bf16.
// 64x64 tiles, grid (16,16).
// =====================================================================
__global__ __launch_bounds__(256) void wtrans(
    const void* __restrict__ W, ushort* __restrict__ Wt,
    const int* __restrict__ modes, int wslot)
{
    __shared__ ushort T[64][68];
    const int tid = threadIdx.x;
    const int m = modes[wslot];
    const int k0 = blockIdx.y * 64, n0 = blockIdx.x * 64;

    const int r = tid >> 2, c = (tid & 3) * 16;
    float t[4];
#pragma unroll
    for (int j = 0; j < 4; ++j) {
        load4m(W, m, (size_t)(k0 + r) * DM + n0 + c + 4 * j, t);
#pragma unroll
        for (int i = 0; i < 4; ++i) T[r][c + 4 * j + i] = f2bf(t[i]);
    }
    __syncthreads();

    const int rn = tid >> 2, ck = (tid & 3) * 16;
    union { ushort u[8]; uint4 v; } p0, p1;
#pragma unroll
    for (int j = 0; j < 8; ++j) { p0.u[j] = T[ck + j][rn]; p1.u[j] = T[ck + 8 + j][rn]; }
    ushort* op = &Wt[(size_t)(n0 + rn) * DM + k0 + ck];
    *(uint4*)op = p0.v;
    *(uint4*)(op + 8) = p1.v;
}

// =====================================================================
// MFMA projection GEMM (m97 structure): A[8192,1024] bf16 @ Wt[n][k] bf16
// -> bf16 out.  128x128 tile, BK=32, global_load_lds 16B staging into
// linear LDS, 4 waves x (4x4) 16x16x32 MFMA.  scale folded in epilogue.
// vmode 0: out[b][h][s][d]; vmode 1: out[b][h][d][s] (V transposed).
// =====================================================================
__global__ __launch_bounds__(256) void proj_mfma(
    const ushort* __restrict__ A, const ushort* __restrict__ Wt,
    ushort* __restrict__ Out, int vmode, float scale)
{
    __shared__ __align__(16) ushort Asf[128 * 32];
    __shared__ __align__(16) ushort Bsf[128 * 32];

    const int tid = threadIdx.x;
    const int lane = tid & 63, wv = tid >> 6;
    const int quad = lane >> 4, L = lane & 15;
    const int m0 = blockIdx.y * 128, n0 = blockIdx.x * 128;
    const int wm = (wv >> 1) * 64, wn = (wv & 1) * 64;

    // staging geometry: 8 wave-calls of 1KB fill 8KB; this wave's 2 calls
    const int e0 = (wv * 2 + 0) * 512 + lane * 8;
    const int e1 = (wv * 2 + 1) * 512 + lane * 8;
    const ushort* gA0 = A  + (size_t)(m0 + (e0 >> 5)) * DM + (e0 & 31);
    const ushort* gA1 = A  + (size_t)(m0 + (e1 >> 5)) * DM + (e1 & 31);
    const ushort* gB0 = Wt + (size_t)(n0 + (e0 >> 5)) * DM + (e0 & 31);
    const ushort* gB1 = Wt + (size_t)(n0 + (e1 >> 5)) * DM + (e1 & 31);

    f32x4 acc[4][4];
#pragma unroll
    for (int i = 0; i < 4; ++i)
#pragma unroll
        for (int j = 0; j < 4; ++j) { acc[i][j][0] = 0.f; acc[i][j][1] = 0.f; acc[i][j][2] = 0.f; acc[i][j][3] = 0.f; }

    for (int kt = 0; kt < 32; ++kt) {
        const int k0 = kt * 32;
        gl_lds16(gA0 + k0, &Asf[e0]);
        gl_lds16(gA1 + k0, &Asf[e1]);
        gl_lds16(gB0 + k0, &Bsf[e0]);
        gl_lds16(gB1 + k0, &Bsf[e1]);
        __syncthreads();   // drains vmcnt -> staged data visible

        bf16x8 af[4], bfr[4];
#pragma unroll
        for (int tm = 0; tm < 4; ++tm) af[tm] = *(const bf16x8*)&Asf[(wm + tm * 16 + L) * 32 + quad * 8];
#pragma unroll
        for (int tn = 0; tn < 4; ++tn) bfr[tn] = *(const bf16x8*)&Bsf[(wn + tn * 16 + L) * 32 + quad * 8];
#pragma unroll
        for (int tm = 0; tm < 4; ++tm)
#pragma unroll
            for (int tn = 0; tn < 4; ++tn)
                acc[tm][tn] = MFMA16(af[tm], bfr[tn], acc[tm][tn]);
        __syncthreads();   // frag reads done before next restage
    }

#pragma unroll
    for (int tm = 0; tm < 4; ++tm)
#pragma unroll
        for (int tn = 0; tn < 4; ++tn)
#pragma unroll
            for (int r = 0; r < 4; ++r) {
                const int mm = m0 + wm + tm * 16 + quad * 4 + r;
                const int n = n0 + wn + tn * 16 + L;
                const int b = mm >> 11, s = mm & 2047;
                const int h = n >> 6, d = n & 63;
                const size_t o = vmode
                    ? ((size_t)(b * HH + h) * DKV + d) * SS + s
                    : ((size_t)(b * HH + h) * SS + s) * DKV + d;
                Out[o] = f2bf(acc[tm][tn][r] * scale);
            }
}

// =====================================================================
// MFMA flash attention, fixed-base softmax (Q pre-scaled by 1/8).
// Mask consumed as packed bitmask (2 MB, L2-resident).
// =====================================================================
__global__ __launch_bounds__(256) void attn_mfma(
    const ushort* __restrict__ Q, const ushort* __restrict__ K,
    const ushort* __restrict__ Vt, const unsigned int* __restrict__ pm,
    ushort* __restrict__ Xo)
{
    __shared__ __align__(16) ushort Ks[64][72];
    __shared__ __align__(16) ushort Vs[64][72];
    __shared__ __align__(16) ushort Ps[64][72];

    const int tid = threadIdx.x;
    const int lane = tid & 63, wv = tid >> 6;
    const int quad = lane >> 4, L = lane & 15;
    const int bh = blockIdx.y, b = bh >> 4, h = bh & 15;
    const int q0 = blockIdx.x * 64;

    const ushort* qp = &Q[((size_t)bh * SS + q0 + wv * 16 + L) * DKV + quad * 8];
    const bf16x8 aq0 = *(const bf16x8*)qp;
    const bf16x8 aq1 = *(const bf16x8*)(qp + 32);

    f32x4 O[4];
    float lacc[4];
#pragma unroll
    for (int t = 0; t < 4; ++t) { O[t][0] = 0.f; O[t][1] = 0.f; O[t][2] = 0.f; O[t][3] = 0.f; }
#pragma unroll
    for (int r = 0; r < 4; ++r) lacc[r] = 0.f;

    const int sr = tid >> 2, sg = tid & 3;
    const ushort* kbase = &K[((size_t)bh * SS + sr) * DKV + sg * 16];
    const ushort* vbase = &Vt[((size_t)bh * DKV + sr) * SS + sg * 16];
    const unsigned int* pmr[4];
#pragma unroll
    for (int r = 0; r < 4; ++r)
        pmr[r] = pm + ((size_t)b * SS + q0 + wv * 16 + quad * 4 + r) * 64;

    for (int kt = 0; kt < 32; ++kt) {
        __syncthreads();
        *(uint4*)&Ks[sr][sg * 16]     = *(const uint4*)kbase;
        *(uint4*)&Ks[sr][sg * 16 + 8] = *(const uint4*)(kbase + 8);
        *(uint4*)&Vs[sr][sg * 16]     = *(const uint4*)vbase;
        *(uint4*)&Vs[sr][sg * 16 + 8] = *(const uint4*)(vbase + 8);
        kbase += 64 * DKV;
        vbase += 64;

        uint2 mw[4];
#pragma unroll
        for (int r = 0; r < 4; ++r) mw[r] = *(const uint2*)(pmr[r] + 2 * kt);

        __syncthreads();

        f32x4 sc[4];
#pragma unroll
        for (int t = 0; t < 4; ++t) {
            bf16x8 b0 = *(const bf16x8*)&Ks[t * 16 + L][quad * 8];
            bf16x8 b1 = *(const bf16x8*)&Ks[t * 16 + L][32 + quad * 8];
            f32x4 c; c[0] = 0.f; c[1] = 0.f; c[2] = 0.f; c[3] = 0.f;
            c = MFMA16(aq0, b0, c);
            c = MFMA16(aq1, b1, c);
            sc[t] = c;
        }

#pragma unroll
        for (int r = 0; r < 4; ++r) {
            const unsigned mx = mw[r].x, my = mw[r].y;
#pragma unroll
            for (int t = 0; t < 4; ++t) {
                const float s = fminf(sc[t][r], 30.f);
                const float e = __expf(s);
                const unsigned wsel = (t & 2) ? my : mx;
                const float p = ((wsel >> ((t & 1) * 16 + L)) & 1u) ? e : 0.f;
                lacc[r] += p;
                Ps[wv * 16 + quad * 4 + r][t * 16 + L] = f2bf_t(p);
            }
        }

        bf16x8 ap0 = *(const bf16x8*)&Ps[wv * 16 + L][quad * 8];
        bf16x8 ap1 = *(const bf16x8*)&Ps[wv * 16 + L][32 + quad * 8];
#pragma unroll
        for (int t = 0; t < 4; ++t) {
            bf16x8 v0 = *(const bf16x8*)&Vs[t * 16 + L][quad * 8];
            bf16x8 v1 = *(const bf16x8*)&Vs[t * 16 + L][32 + quad * 8];
            O[t] = MFMA16(ap0, v0, O[t]);
            O[t] = MFMA16(ap1, v1, O[t]);
        }
    }

    float inv[4];
#pragma unroll
    for (int r = 0; r < 4; ++r) {
        float l = lacc[r];
#pragma unroll
        for (int off = 1; off < 16; off <<= 1) l += __shfl_xor(l, off, 64);
        inv[r] = 1.f / l;
    }
#pragma unroll
    for (int t = 0; t < 4; ++t)
#pragma unroll
        for (int r = 0; r < 4; ++r) {
            const int qg = q0 + wv * 16 + quad * 4 + r;
            Xo[((size_t)b * SS + qg) * DM + h * DKV + t * 16 + L] = f2bf(O[t][r] * inv[r]);
        }
}

// =====================================================================
// MFMA output projection (m97 structure): X(bf16) @ Wt_out + query -> fp32.
// =====================================================================
__global__ __launch_bounds__(256) void oproj_mfma(
    const ushort* __restrict__ Xin, const ushort* __restrict__ Wt,
    const void* __restrict__ Qres, float* __restrict__ Out,
    const int* __restrict__ modes)
{
    __shared__ __align__(16) ushort Asf[128 * 32];
    __shared__ __align__(16) ushort Bsf[128 * 32];

    const int tid = threadIdx.x;
    const int lane = tid & 63, wv = tid >> 6;
    const int quad = lane >> 4, L = lane & 15;
    const int m0 = blockIdx.y * 128, n0 = blockIdx.x * 128;
    const int wm = (wv >> 1) * 64, wn = (wv & 1) * 64;
    const int mq = modes[0];

    const int e0 = (wv * 2 + 0) * 512 + lane * 8;
    const int e1 = (wv * 2 + 1) * 512 + lane * 8;
    const ushort* gA0 = Xin + (size_t)(m0 + (e0 >> 5)) * DM + (e0 & 31);
    const ushort* gA1 = Xin + (size_t)(m0 + (e1 >> 5)) * DM + (e1 & 31);
    const ushort* gB0 = Wt  + (size_t)(n0 + (e0 >> 5)) * DM + (e0 & 31);
    const ushort* gB1 = Wt  + (size_t)(n0 + (e1 >> 5)) * DM + (e1 & 31);

    f32x4 acc[4][4];
#pragma unroll
    for (int i = 0; i < 4; ++i)
#pragma unroll
        for (int j = 0; j < 4; ++j) { acc[i][j][0] = 0.f; acc[i][j][1] = 0.f; acc[i][j][2] = 0.f; acc[i][j][3] = 0.f; }

    for (int kt = 0; kt < 32; ++kt) {
        const int k0 = kt * 32;
        gl_lds16(gA0 + k0, &Asf[e0]);
        gl_lds16(gA1 + k0, &Asf[e1]);
        gl_lds16(gB0 + k0, &Bsf[e0]);
        gl_lds16(gB1 + k0, &Bsf[e1]);
        __syncthreads();

        bf16x8 af[4], bfr[4];
#pragma unroll
        for (int tm = 0; tm < 4; ++tm) af[tm] = *(const bf16x8*)&Asf[(wm + tm * 16 + L) * 32 + quad * 8];
#pragma unroll
        for (int tn = 0; tn < 4; ++tn) bfr[tn] = *(const bf16x8*)&Bsf[(wn + tn * 16 + L) * 32 + quad * 8];
#pragma unroll
        for (int tm = 0; tm < 4; ++tm)
#pragma unroll
            for (int tn = 0; tn < 4; ++tn)
                acc[tm][tn] = MFMA16(af[tm], bfr[tn], acc[tm][tn]);
        __syncthreads();
    }

#pragma unroll
    for (int tm = 0; tm < 4; ++tm)
#pragma unroll
        for (int tn = 0; tn < 4; ++tn)
#pragma unroll
            for (int r = 0; r < 4; ++r) {
                const int mm = m0 + wm + tm * 16 + quad * 4 + r;
                const int n = n0 + wn + tn * 16 + L;
                const size_t idx = (size_t)mm * DM + n;
                Out[idx] = acc[tm][tn][r] + loadS(Qres, mq, idx);
            }
}

// =====================================================================
// In-place LayerNorm over d_out rows (8192 x 1024 fp32), 1 row per wave.
// =====================================================================
__global__ __launch_bounds__(256) void ln_k(
    float* __restrict__ Out, const void* __restrict__ G,
    const void* __restrict__ Bt, const int* __restrict__ modes)
{
    const int tid = threadIdx.x, wv = tid >> 6, lane = tid & 63;
    const int row = blockIdx.x * 4 + wv;
    const int mg = modes[8], mb = modes[9];
    const size_t base = (size_t)row * DM + lane * 16;

    float v[16];
    float s = 0.f, q = 0.f;
#pragma unroll
    for (int j = 0; j < 16; j += 4) {
        float4 t = *(const float4*)&Out[base + j];
        v[j] = t.x; v[j+1] = t.y; v[j+2] = t.z; v[j+3] = t.w;
        s += t.x + t.y + t.z + t.w;
        q += t.x*t.x + t.y*t.y + t.z*t.z + t.w*t.w;
    }
#pragma unroll
    for (int off = 1; off < 64; off <<= 1) {
        s += __shfl_xor(s, off, 64);
        q += __shfl_xor(q, off, 64);
    }
    const float mu = s * (1.f / 1024.f);
    const float var = q * (1.f / 1024.f) - mu * mu;
    const float inv = rsqrtf(var + LNEPS);

    float gj[16], bj[16];
#pragma unroll
    for (int j = 0; j < 16; j += 4) {
        load4m(G,  mg, (size_t)lane * 16 + j, gj + j);
        load4m(Bt, mb, (size_t)lane * 16 + j, bj + j);
    }
#pragma unroll
    for (int j = 0; j < 16; j += 4) {
        float4 o;
        o.x = (v[j]   - mu) * inv * gj[j]   + bj[j];
        o.y = (v[j+1] - mu) * inv * gj[j+1] + bj[j+1];
        o.z = (v[j+2] - mu) * inv * gj[j+2] + bj[j+2];
        o.w = (v[j+3] - mu) * inv * gj[j+3] + bj[j+3];
        *(float4*)&Out[base + j] = o;
    }
}

// =====================================================================
extern "C" void kernel_launch(void* const* d_in, const int* in_sizes, int n_in,
                              void* d_out, int out_size, void* d_ws, size_t ws_size,
                              hipStream_t stream)
{
    const void* query = d_in[0];
    const void* key_i = d_in[1];
    const void* value = d_in[2];
    const int*  mask  = (const int*)d_in[3];
    const void* w_qs  = d_in[4];
    const void* w_ks  = d_in[5];
    const void* w_vs  = d_in[6];
    const void* w_out = d_in[7];
    const void* ln_g  = d_in[8];
    const void* ln_b  = d_in[9];
    float* out = (float*)d_out;

    // ws layout: [modes 256B][Qw 16MB][Kw 16MB][Vw 16MB][Xw 16MB]
    // Abuf (bf16 A for projections) aliases the not-yet-written Xw region.
    // Wt (proj weights, 2MB) lives in d_out+4MB (dead until oproj).
    // pmask (2MB) lives in d_out+0.  Wt2 (w_out) aliases dead-after-attn Qw.
    int* modes = (int*)d_ws;
    const size_t PE = (size_t)BB * HH * SS * DKV;  // 8,388,608
    ushort* Qw = (ushort*)((char*)d_ws + 256);
    ushort* Kw = Qw + PE;
    ushort* Vw = Kw + PE;   // transposed layout [bh][d][s]
    ushort* Xw = Vw + PE;
    ushort* Abuf = Xw;                               // 16MB, pre-attn only
    ushort* Wt   = (ushort*)((char*)d_out + (4 << 20));  // 2MB scratch
    ushort* Wt2  = Qw;                               // 2MB, post-attn
    unsigned int* pmask = (unsigned int*)d_out;      // 2MB packed mask

    SniffArgs sa;
    for (int i = 0; i < 10; ++i) {
        sa.p[i] = d_in[i];
        sa.nhalf[i] = in_sizes[i] < 4096 ? in_sizes[i] : 4096;
    }
    sniff_all<<<9, 256, 0, stream>>>(sa, modes);
    mpack<<<2048, 256, 0, stream>>>(mask, pmask);

    dim3 gproj(8, 64), gtr(16, 16);

    wtrans<<<gtr, 256, 0, stream>>>(w_qs, Wt, modes, 4);
    aconv<<<2048, 256, 0, stream>>>(query, Abuf, modes, 0);
    proj_mfma<<<gproj, 256, 0, stream>>>(Abuf, Wt, Qw, 0, 0.125f);

    wtrans<<<gtr, 256, 0, stream>>>(w_ks, Wt, modes, 5);
    aconv<<<2048, 256, 0, stream>>>(key_i, Abuf, modes, 1);
    proj_mfma<<<gproj, 256, 0, stream>>>(Abuf, Wt, Kw, 0, 1.0f);

    wtrans<<<gtr, 256, 0, stream>>>(w_vs, Wt, modes, 6);
    aconv<<<2048, 256, 0, stream>>>(value, Abuf, modes, 2);
    proj_mfma<<<gproj, 256, 0, stream>>>(Abuf, Wt, Vw, 1, 1.0f);

    attn_mfma<<<dim3(32, 64), 256, 0, stream>>>(Qw, Kw, Vw, pmask, Xw);

    wtrans<<<gtr, 256, 0, stream>>>(w_out, Wt2, modes, 7);
    oproj_mfma<<<gproj, 256, 0, stream>>>(Xw, Wt2, query, out, modes);
    ln_k<<<2048, 256, 0, stream>>>(out, ln_g, ln_b, modes);
}

// Round 3
// 527.144 us; speedup vs baseline: 1.1458x; 1.0175x over previous
//
#include <hip/hip_runtime.h>

#define BB   4
#define SS   2048
#define HH   16
#define DM   1024
#define DKV  64
#define LNEPS 1e-6f

#define MD_BF16 0
#define MD_F32  1
#define MD_F16  2

typedef __attribute__((ext_vector_type(8))) short bf16x8;
typedef __attribute__((ext_vector_type(4))) float f32x4;
#define MFMA16(a,b,c) __builtin_amdgcn_mfma_f32_16x16x32_bf16(a,b,c,0,0,0)

// async global->LDS DMA, 16B per lane (dest = wave-uniform base + lane*16)
__device__ __forceinline__ void gl_lds16(const ushort* g, ushort* l) {
    __builtin_amdgcn_global_load_lds(
        (const __attribute__((address_space(1))) void*)g,
        (__attribute__((address_space(3))) void*)l, 16, 0, 0);
}
__device__ __forceinline__ void wait_vm0_barrier() {
    asm volatile("s_waitcnt vmcnt(0)" ::: "memory");
    __builtin_amdgcn_s_barrier();
}

// ---------- dtype helpers ----------
__device__ __forceinline__ float2 unpack2(unsigned int u) {
    union { unsigned int i; float f; } a, b;
    a.i = u << 16;
    b.i = u & 0xffff0000u;
    return make_float2(a.f, b.f);
}
__device__ __forceinline__ unsigned short f2bf(float f) {   // RNE
    union { float f; unsigned int i; } c; c.f = f;
    unsigned int u = c.i;
    unsigned int r = u + 0x7fffu + ((u >> 16) & 1u);
    return (unsigned short)(r >> 16);
}
__device__ __forceinline__ unsigned short f2bf_t(float f) { // truncate
    union { float f; unsigned int i; } c; c.f = f;
    return (unsigned short)(c.i >> 16);
}
__device__ __forceinline__ float h2f(unsigned int bits16) {
    unsigned short s = (unsigned short)bits16;
    _Float16 x;
    __builtin_memcpy(&x, &s, 2);
    return (float)x;
}
__device__ __forceinline__ void load8m(const void* p, int mode, size_t e0, float* o) {
    if (mode == MD_F32) {
        const float* f = (const float*)p + e0;
        float4 a = *(const float4*)f;
        float4 b = *(const float4*)(f + 4);
        o[0] = a.x; o[1] = a.y; o[2] = a.z; o[3] = a.w;
        o[4] = b.x; o[5] = b.y; o[6] = b.z; o[7] = b.w;
    } else {
        uint4 u = *(const uint4*)((const ushort*)p + e0);
        unsigned v[4] = {u.x, u.y, u.z, u.w};
        if (mode == MD_BF16) {
#pragma unroll
            for (int j = 0; j < 4; ++j) { float2 t = unpack2(v[j]); o[2*j] = t.x; o[2*j+1] = t.y; }
        } else {
#pragma unroll
            for (int j = 0; j < 4; ++j) { o[2*j] = h2f(v[j] & 0xFFFFu); o[2*j+1] = h2f(v[j] >> 16); }
        }
    }
}
__device__ __forceinline__ void load4m(const void* p, int mode, size_t e0, float* o) {
    if (mode == MD_F32) {
        float4 v = *(const float4*)((const float*)p + e0);
        o[0] = v.x; o[1] = v.y; o[2] = v.z; o[3] = v.w;
    } else {
        uint2 u = *(const uint2*)((const ushort*)p + e0);
        if (mode == MD_BF16) {
            float2 a = unpack2(u.x), b = unpack2(u.y);
            o[0] = a.x; o[1] = a.y; o[2] = b.x; o[3] = b.y;
        } else {
            o[0] = h2f(u.x & 0xFFFFu); o[1] = h2f(u.x >> 16);
            o[2] = h2f(u.y & 0xFFFFu); o[3] = h2f(u.y >> 16);
        }
    }
}
__device__ __forceinline__ float loadS(const void* p, int mode, size_t i) {
    if (mode == MD_F32) return ((const float*)p)[i];
    unsigned short u = ((const ushort*)p)[i];
    if (mode == MD_BF16) { union { unsigned i; float f; } c; c.i = (unsigned)u << 16; return c.f; }
    return h2f(u);
}

// =====================================================================
// Fused dtype sniff: one block per float tensor.
// =====================================================================
struct SniffArgs { const void* p[10]; int nhalf[10]; };

__global__ void sniff_all(SniffArgs a, int* __restrict__ modes) {
    __shared__ int cE, cO;
    const int slots[9] = {0, 1, 2, 4, 5, 6, 7, 8, 9};
    const int slot = slots[blockIdx.x];
    const ushort* p = (const ushort*)a.p[slot];
    const int nhalf = a.nhalf[slot];
    if (threadIdx.x == 0) { cE = 0; cO = 0; }
    __syncthreads();
    int e = 0, o = 0;
    for (int i = threadIdx.x; i < nhalf; i += 256) {
        unsigned ex = (p[i] >> 7) & 0xFFu;
        int hit = (ex < 100u || ex == 0xFFu) ? 1 : 0;
        if (i & 1) o += hit; else e += hit;
    }
    atomicAdd(&cE, e);
    atomicAdd(&cO, o);
    __syncthreads();
    if (threadIdx.x == 0) {
        int total = cE + cO;
        modes[slot] = (total < 48) ? MD_BF16 : ((cO * 4 < cE) ? MD_F32 : MD_F16);
    }
}

// =====================================================================
// Mask bit-pack: mask[B][S][S] int32 -> 1 bit/elem (2 MB, L2-resident).
// =====================================================================
__global__ __launch_bounds__(256) void mpack(
    const int* __restrict__ mask, unsigned int* __restrict__ pm)
{
    const int w = blockIdx.x * 256 + threadIdx.x;
    const int* p = mask + (size_t)w * 32;
    unsigned int bits = 0u;
#pragma unroll
    for (int j = 0; j < 8; ++j) {
        int4 v = *(const int4*)(p + j * 4);
        bits |= (v.x ? 1u : 0u) << (4 * j);
        bits |= (v.y ? 1u : 0u) << (4 * j + 1);
        bits |= (v.z ? 1u : 0u) << (4 * j + 2);
        bits |= (v.w ? 1u : 0u) << (4 * j + 3);
    }
    pm[w] = bits;
}

// =====================================================================
// A-convert: any sniffed dtype -> bf16, 16 elems/thread. grid 2048x256.
// =====================================================================
__global__ __launch_bounds__(256) void aconv(
    const void* __restrict__ A, ushort* __restrict__ Ab,
    const int* __restrict__ modes, int slot)
{
    const int m = modes[slot];
    const size_t e0 = ((size_t)blockIdx.x * 256 + threadIdx.x) * 16;
    float t[16];
    load8m(A, m, e0, t);
    load8m(A, m, e0 + 8, t + 8);
    union { ushort u[16]; uint4 v[2]; } p;
#pragma unroll
    for (int j = 0; j < 16; ++j) p.u[j] = f2bf(t[j]);
    *(uint4*)&Ab[e0]     = p.v[0];
    *(uint4*)&Ab[e0 + 8] = p.v[1];
}

// =====================================================================
// Weight transpose + bf16 convert: W[k][n] (any dtype) -> Wt[n][k] bf16.
// 64x64 tiles, grid (16,16,ngroup) — z selects the weight tensor.
// =====================================================================
struct WtArgs { const void* W[3]; ushort* Wt[3]; int slot[3]; };

__device__ __forceinline__ void wtrans_body(
    const void* __restrict__ W, ushort* __restrict__ Wt, int m)
{
    __shared__ ushort T[64][68];
    const int tid = threadIdx.x;
    const int k0 = blockIdx.y * 64, n0 = blockIdx.x * 64;

    const int r = tid >> 2, c = (tid & 3) * 16;
    float t[4];
#pragma unroll
    for (int j = 0; j < 4; ++j) {
        load4m(W, m, (size_t)(k0 + r) * DM + n0 + c + 4 * j, t);
#pragma unroll
        for (int i = 0; i < 4; ++i) T[r][c + 4 * j + i] = f2bf(t[i]);
    }
    __syncthreads();

    const int rn = tid >> 2, ck = (tid & 3) * 16;
    union { ushort u[8]; uint4 v; } p0, p1;
#pragma unroll
    for (int j = 0; j < 8; ++j) { p0.u[j] = T[ck + j][rn]; p1.u[j] = T[ck + 8 + j][rn]; }
    ushort* op = &Wt[(size_t)(n0 + rn) * DM + k0 + ck];
    *(uint4*)op = p0.v;
    *(uint4*)(op + 8) = p1.v;
}

__global__ __launch_bounds__(256) void wtrans3(WtArgs a, const int* __restrict__ modes) {
    const int g = blockIdx.z;
    wtrans_body(a.W[g], a.Wt[g], modes[a.slot[g]]);
}
__global__ __launch_bounds__(256) void wtrans(
    const void* __restrict__ W, ushort* __restrict__ Wt,
    const int* __restrict__ modes, int wslot)
{
    wtrans_body(W, Wt, modes[wslot]);
}

// =====================================================================
// MFMA projection GEMM: A[8192,1024] bf16 @ Wt[n][k] bf16 -> bf16 out.
// 128x128 tile, BK=32, double-buffered global_load_lds staging with
// counted-vmcnt raw barriers (T3-minimum 2-phase), XCD-chunked swizzle
// (all 8 N-tiles of an A-panel land on one XCD -> 4MB L2 working set).
// vmode 0: out[b][h][s][d]; vmode 1: out[b][h][d][s] (V transposed).
// =====================================================================
__global__ __launch_bounds__(256) void proj_mfma(
    const ushort* __restrict__ A, const ushort* __restrict__ Wt,
    ushort* __restrict__ Out, int vmode, float scale)
{
    __shared__ __align__(16) ushort Asf[2][4096];
    __shared__ __align__(16) ushort Bsf[2][4096];

    const int tid = threadIdx.x;
    const int lane = tid & 63, wv = tid >> 6;
    const int quad = lane >> 4, L = lane & 15;
    const int bid = blockIdx.y * gridDim.x + blockIdx.x;   // 512, x fastest
    const int swz = (bid & 7) * 64 + (bid >> 3);           // XCD-chunked
    const int m0 = (swz >> 3) * 128, n0 = (swz & 7) * 128;
    const int wm = (wv >> 1) * 64, wn = (wv & 1) * 64;

    const int e0 = (wv * 2 + 0) * 512 + lane * 8;
    const int e1 = (wv * 2 + 1) * 512 + lane * 8;
    const ushort* gA0 = A  + (size_t)(m0 + (e0 >> 5)) * DM + (e0 & 31);
    const ushort* gA1 = A  + (size_t)(m0 + (e1 >> 5)) * DM + (e1 & 31);
    const ushort* gB0 = Wt + (size_t)(n0 + (e0 >> 5)) * DM + (e0 & 31);
    const ushort* gB1 = Wt + (size_t)(n0 + (e1 >> 5)) * DM + (e1 & 31);

    f32x4 acc[4][4];
#pragma unroll
    for (int i = 0; i < 4; ++i)
#pragma unroll
        for (int j = 0; j < 4; ++j) { acc[i][j][0] = 0.f; acc[i][j][1] = 0.f; acc[i][j][2] = 0.f; acc[i][j][3] = 0.f; }

    // prologue: stage tile 0 into buf 0
    gl_lds16(gA0, &Asf[0][e0]);
    gl_lds16(gA1, &Asf[0][e1]);
    gl_lds16(gB0, &Bsf[0][e0]);
    gl_lds16(gB1, &Bsf[0][e1]);
    wait_vm0_barrier();

    int cur = 0;
    for (int kt = 0; kt < 31; ++kt) {
        const int kn = (kt + 1) * 32;
        // issue next tile's loads FIRST — they fly across the compute phase
        gl_lds16(gA0 + kn, &Asf[cur ^ 1][e0]);
        gl_lds16(gA1 + kn, &Asf[cur ^ 1][e1]);
        gl_lds16(gB0 + kn, &Bsf[cur ^ 1][e0]);
        gl_lds16(gB1 + kn, &Bsf[cur ^ 1][e1]);

        bf16x8 af[4], bfr[4];
#pragma unroll
        for (int tm = 0; tm < 4; ++tm) af[tm] = *(const bf16x8*)&Asf[cur][(wm + tm * 16 + L) * 32 + quad * 8];
#pragma unroll
        for (int tn = 0; tn < 4; ++tn) bfr[tn] = *(const bf16x8*)&Bsf[cur][(wn + tn * 16 + L) * 32 + quad * 8];
#pragma unroll
        for (int tm = 0; tm < 4; ++tm)
#pragma unroll
            for (int tn = 0; tn < 4; ++tn)
                acc[tm][tn] = MFMA16(af[tm], bfr[tn], acc[tm][tn]);

        wait_vm0_barrier();   // next tile staged; all waves done reading cur
        cur ^= 1;
    }
    {   // tail tile
        bf16x8 af[4], bfr[4];
#pragma unroll
        for (int tm = 0; tm < 4; ++tm) af[tm] = *(const bf16x8*)&Asf[cur][(wm + tm * 16 + L) * 32 + quad * 8];
#pragma unroll
        for (int tn = 0; tn < 4; ++tn) bfr[tn] = *(const bf16x8*)&Bsf[cur][(wn + tn * 16 + L) * 32 + quad * 8];
#pragma unroll
        for (int tm = 0; tm < 4; ++tm)
#pragma unroll
            for (int tn = 0; tn < 4; ++tn)
                acc[tm][tn] = MFMA16(af[tm], bfr[tn], acc[tm][tn]);
    }

#pragma unroll
    for (int tm = 0; tm < 4; ++tm)
#pragma unroll
        for (int tn = 0; tn < 4; ++tn)
#pragma unroll
            for (int r = 0; r < 4; ++r) {
                const int mm = m0 + wm + tm * 16 + quad * 4 + r;
                const int n = n0 + wn + tn * 16 + L;
                const int b = mm >> 11, s = mm & 2047;
                const int h = n >> 6, d = n & 63;
                const size_t o = vmode
                    ? ((size_t)(b * HH + h) * DKV + d) * SS + s
                    : ((size_t)(b * HH + h) * SS + s) * DKV + d;
                Out[o] = f2bf(acc[tm][tn][r] * scale);
            }
}

// =====================================================================
// MFMA flash attention, fixed-base softmax (Q pre-scaled by 1/8).
// Packed bitmask (2 MB, L2-resident).  XCD-chunked swizzle: each XCD
// owns 8 complete bh (4MB K/V working set).  setprio around MFMA.
// =====================================================================
__global__ __launch_bounds__(256) void attn_mfma(
    const ushort* __restrict__ Q, const ushort* __restrict__ K,
    const ushort* __restrict__ Vt, const unsigned int* __restrict__ pm,
    ushort* __restrict__ Xo)
{
    __shared__ __align__(16) ushort Ks[64][72];
    __shared__ __align__(16) ushort Vs[64][72];
    __shared__ __align__(16) ushort Ps[64][72];

    const int tid = threadIdx.x;
    const int lane = tid & 63, wv = tid >> 6;
    const int quad = lane >> 4, L = lane & 15;
    const int bid = blockIdx.y * gridDim.x + blockIdx.x;   // 2048, x fastest
    const int swz = (bid & 7) * 256 + (bid >> 3);          // XCD-chunked
    const int bh = swz >> 5, b = bh >> 4, h = bh & 15;
    const int q0 = (swz & 31) * 64;

    const ushort* qp = &Q[((size_t)bh * SS + q0 + wv * 16 + L) * DKV + quad * 8];
    const bf16x8 aq0 = *(const bf16x8*)qp;
    const bf16x8 aq1 = *(const bf16x8*)(qp + 32);

    f32x4 O[4];
    float lacc[4];
#pragma unroll
    for (int t = 0; t < 4; ++t) { O[t][0] = 0.f; O[t][1] = 0.f; O[t][2] = 0.f; O[t][3] = 0.f; }
#pragma unroll
    for (int r = 0; r < 4; ++r) lacc[r] = 0.f;

    const int sr = tid >> 2, sg = tid & 3;
    const ushort* kbase = &K[((size_t)bh * SS + sr) * DKV + sg * 16];
    const ushort* vbase = &Vt[((size_t)bh * DKV + sr) * SS + sg * 16];
    const unsigned int* pmr[4];
#pragma unroll
    for (int r = 0; r < 4; ++r)
        pmr[r] = pm + ((size_t)b * SS + q0 + wv * 16 + quad * 4 + r) * 64;

    for (int kt = 0; kt < 32; ++kt) {
        __syncthreads();
        *(uint4*)&Ks[sr][sg * 16]     = *(const uint4*)kbase;
        *(uint4*)&Ks[sr][sg * 16 + 8] = *(const uint4*)(kbase + 8);
        *(uint4*)&Vs[sr][sg * 16]     = *(const uint4*)vbase;
        *(uint4*)&Vs[sr][sg * 16 + 8] = *(const uint4*)(vbase + 8);
        kbase += 64 * DKV;
        vbase += 64;

        uint2 mw[4];
#pragma unroll
        for (int r = 0; r < 4; ++r) mw[r] = *(const uint2*)(pmr[r] + 2 * kt);

        __syncthreads();

        f32x4 sc[4];
        __builtin_amdgcn_s_setprio(1);
#pragma unroll
        for (int t = 0; t < 4; ++t) {
            bf16x8 b0 = *(const bf16x8*)&Ks[t * 16 + L][quad * 8];
            bf16x8 b1 = *(const bf16x8*)&Ks[t * 16 + L][32 + quad * 8];
            f32x4 c; c[0] = 0.f; c[1] = 0.f; c[2] = 0.f; c[3] = 0.f;
            c = MFMA16(aq0, b0, c);
            c = MFMA16(aq1, b1, c);
            sc[t] = c;
        }
        __builtin_amdgcn_s_setprio(0);

#pragma unroll
        for (int r = 0; r < 4; ++r) {
            const unsigned mx = mw[r].x, my = mw[r].y;
#pragma unroll
            for (int t = 0; t < 4; ++t) {
                const float s = fminf(sc[t][r], 30.f);
                const float e = __expf(s);
                const unsigned wsel = (t & 2) ? my : mx;
                const float p = ((wsel >> ((t & 1) * 16 + L)) & 1u) ? e : 0.f;
                lacc[r] += p;
                Ps[wv * 16 + quad * 4 + r][t * 16 + L] = f2bf_t(p);
            }
        }

        bf16x8 ap0 = *(const bf16x8*)&Ps[wv * 16 + L][quad * 8];
        bf16x8 ap1 = *(const bf16x8*)&Ps[wv * 16 + L][32 + quad * 8];
        __builtin_amdgcn_s_setprio(1);
#pragma unroll
        for (int t = 0; t < 4; ++t) {
            bf16x8 v0 = *(const bf16x8*)&Vs[t * 16 + L][quad * 8];
            bf16x8 v1 = *(const bf16x8*)&Vs[t * 16 + L][32 + quad * 8];
            O[t] = MFMA16(ap0, v0, O[t]);
            O[t] = MFMA16(ap1, v1, O[t]);
        }
        __builtin_amdgcn_s_setprio(0);
    }

    float inv[4];
#pragma unroll
    for (int r = 0; r < 4; ++r) {
        float l = lacc[r];
#pragma unroll
        for (int off = 1; off < 16; off <<= 1) l += __shfl_xor(l, off, 64);
        inv[r] = 1.f / l;
    }
#pragma unroll
    for (int t = 0; t < 4; ++t)
#pragma unroll
        for (int r = 0; r < 4; ++r) {
            const int qg = q0 + wv * 16 + quad * 4 + r;
            Xo[((size_t)b * SS + qg) * DM + h * DKV + t * 16 + L] = f2bf(O[t][r] * inv[r]);
        }
}

// =====================================================================
// MFMA output projection: X(bf16) @ Wt_out + query -> fp32.  Same dbuf +
// swizzle structure as proj_mfma.
// =====================================================================
__global__ __launch_bounds__(256) void oproj_mfma(
    const ushort* __restrict__ Xin, const ushort* __restrict__ Wt,
    const void* __restrict__ Qres, float* __restrict__ Out,
    const int* __restrict__ modes)
{
    __shared__ __align__(16) ushort Asf[2][4096];
    __shared__ __align__(16) ushort Bsf[2][4096];

    const int tid = threadIdx.x;
    const int lane = tid & 63, wv = tid >> 6;
    const int quad = lane >> 4, L = lane & 15;
    const int bid = blockIdx.y * gridDim.x + blockIdx.x;
    const int swz = (bid & 7) * 64 + (bid >> 3);
    const int m0 = (swz >> 3) * 128, n0 = (swz & 7) * 128;
    const int wm = (wv >> 1) * 64, wn = (wv & 1) * 64;
    const int mq = modes[0];

    const int e0 = (wv * 2 + 0) * 512 + lane * 8;
    const int e1 = (wv * 2 + 1) * 512 + lane * 8;
    const ushort* gA0 = Xin + (size_t)(m0 + (e0 >> 5)) * DM + (e0 & 31);
    const ushort* gA1 = Xin + (size_t)(m0 + (e1 >> 5)) * DM + (e1 & 31);
    const ushort* gB0 = Wt  + (size_t)(n0 + (e0 >> 5)) * DM + (e0 & 31);
    const ushort* gB1 = Wt  + (size_t)(n0 + (e1 >> 5)) * DM + (e1 & 31);

    f32x4 acc[4][4];
#pragma unroll
    for (int i = 0; i < 4; ++i)
#pragma unroll
        for (int j = 0; j < 4; ++j) { acc[i][j][0] = 0.f; acc[i][j][1] = 0.f; acc[i][j][2] = 0.f; acc[i][j][3] = 0.f; }

    gl_lds16(gA0, &Asf[0][e0]);
    gl_lds16(gA1, &Asf[0][e1]);
    gl_lds16(gB0, &Bsf[0][e0]);
    gl_lds16(gB1, &Bsf[0][e1]);
    wait_vm0_barrier();

    int cur = 0;
    for (int kt = 0; kt < 31; ++kt) {
        const int kn = (kt + 1) * 32;
        gl_lds16(gA0 + kn, &Asf[cur ^ 1][e0]);
        gl_lds16(gA1 + kn, &Asf[cur ^ 1][e1]);
        gl_lds16(gB0 + kn, &Bsf[cur ^ 1][e0]);
        gl_lds16(gB1 + kn, &Bsf[cur ^ 1][e1]);

        bf16x8 af[4], bfr[4];
#pragma unroll
        for (int tm = 0; tm < 4; ++tm) af[tm] = *(const bf16x8*)&Asf[cur][(wm + tm * 16 + L) * 32 + quad * 8];
#pragma unroll
        for (int tn = 0; tn < 4; ++tn) bfr[tn] = *(const bf16x8*)&Bsf[cur][(wn + tn * 16 + L) * 32 + quad * 8];
#pragma unroll
        for (int tm = 0; tm < 4; ++tm)
#pragma unroll
            for (int tn = 0; tn < 4; ++tn)
                acc[tm][tn] = MFMA16(af[tm], bfr[tn], acc[tm][tn]);

        wait_vm0_barrier();
        cur ^= 1;
    }
    {
        bf16x8 af[4], bfr[4];
#pragma unroll
        for (int tm = 0; tm < 4; ++tm) af[tm] = *(const bf16x8*)&Asf[cur][(wm + tm * 16 + L) * 32 + quad * 8];
#pragma unroll
        for (int tn = 0; tn < 4; ++tn) bfr[tn] = *(const bf16x8*)&Bsf[cur][(wn + tn * 16 + L) * 32 + quad * 8];
#pragma unroll
        for (int tm = 0; tm < 4; ++tm)
#pragma unroll
            for (int tn = 0; tn < 4; ++tn)
                acc[tm][tn] = MFMA16(af[tm], bfr[tn], acc[tm][tn]);
    }

#pragma unroll
    for (int tm = 0; tm < 4; ++tm)
#pragma unroll
        for (int tn = 0; tn < 4; ++tn)
#pragma unroll
            for (int r = 0; r < 4; ++r) {
                const int mm = m0 + wm + tm * 16 + quad * 4 + r;
                const int n = n0 + wn + tn * 16 + L;
                const size_t idx = (size_t)mm * DM + n;
                Out[idx] = acc[tm][tn][r] + loadS(Qres, mq, idx);
            }
}

// =====================================================================
// In-place LayerNorm over d_out rows (8192 x 1024 fp32), 1 row per wave.
// =====================================================================
__global__ __launch_bounds__(256) void ln_k(
    float* __restrict__ Out, const void* __restrict__ G,
    const void* __restrict__ Bt, const int* __restrict__ modes)
{
    const int tid = threadIdx.x, wv = tid >> 6, lane = tid & 63;
    const int row = blockIdx.x * 4 + wv;
    const int mg = modes[8], mb = modes[9];
    const size_t base = (size_t)row * DM + lane * 16;

    float v[16];
    float s = 0.f, q = 0.f;
#pragma unroll
    for (int j = 0; j < 16; j += 4) {
        float4 t = *(const float4*)&Out[base + j];
        v[j] = t.x; v[j+1] = t.y; v[j+2] = t.z; v[j+3] = t.w;
        s += t.x + t.y + t.z + t.w;
        q += t.x*t.x + t.y*t.y + t.z*t.z + t.w*t.w;
    }
#pragma unroll
    for (int off = 1; off < 64; off <<= 1) {
        s += __shfl_xor(s, off, 64);
        q += __shfl_xor(q, off, 64);
    }
    const float mu = s * (1.f / 1024.f);
    const float var = q * (1.f / 1024.f) - mu * mu;
    const float inv = rsqrtf(var + LNEPS);

    float gj[16], bj[16];
#pragma unroll
    for (int j = 0; j < 16; j += 4) {
        load4m(G,  mg, (size_t)lane * 16 + j, gj + j);
        load4m(Bt, mb, (size_t)lane * 16 + j, bj + j);
    }
#pragma unroll
    for (int j = 0; j < 16; j += 4) {
        float4 o;
        o.x = (v[j]   - mu) * inv * gj[j]   + bj[j];
        o.y = (v[j+1] - mu) * inv * gj[j+1] + bj[j+1];
        o.z = (v[j+2] - mu) * inv * gj[j+2] + bj[j+2];
        o.w = (v[j+3] - mu) * inv * gj[j+3] + bj[j+3];
        *(float4*)&Out[base + j] = o;
    }
}

// =====================================================================
extern "C" void kernel_launch(void* const* d_in, const int* in_sizes, int n_in,
                              void* d_out, int out_size, void* d_ws, size_t ws_size,
                              hipStream_t stream)
{
    const void* query = d_in[0];
    const void* key_i = d_in[1];
    const void* value = d_in[2];
    const int*  mask  = (const int*)d_in[3];
    const void* w_qs  = d_in[4];
    const void* w_ks  = d_in[5];
    const void* w_vs  = d_in[6];
    const void* w_out = d_in[7];
    const void* ln_g  = d_in[8];
    const void* ln_b  = d_in[9];
    float* out = (float*)d_out;

    // ws layout: [modes 256B][Qw 16MB][Kw 16MB][Vw 16MB][Xw 16MB]
    // Abuf (bf16 A for projections) aliases the not-yet-written Xw region.
    // d_out (32MB, dead until oproj): pmask@0 (2MB), Wtq/Wtk/Wtv @4/8/12MB.
    // Wt2 (w_out transpose) aliases dead-after-attn Qw — must NOT be in
    // d_out (oproj epilogue would race with its own Wt reads).
    int* modes = (int*)d_ws;
    const size_t PE = (size_t)BB * HH * SS * DKV;  // 8,388,608
    ushort* Qw = (ushort*)((char*)d_ws + 256);
    ushort* Kw = Qw + PE;
    ushort* Vw = Kw + PE;   // transposed layout [bh][d][s]
    ushort* Xw = Vw + PE;
    ushort* Abuf = Xw;                                    // 16MB, pre-attn
    ushort* Wtq  = (ushort*)((char*)d_out + (4  << 20));
    ushort* Wtk  = (ushort*)((char*)d_out + (8  << 20));
    ushort* Wtv  = (ushort*)((char*)d_out + (12 << 20));
    ushort* Wt2  = Qw;                                    // 2MB, post-attn
    unsigned int* pmask = (unsigned int*)d_out;           // 2MB packed mask

    SniffArgs sa;
    for (int i = 0; i < 10; ++i) {
        sa.p[i] = d_in[i];
        sa.nhalf[i] = in_sizes[i] < 4096 ? in_sizes[i] : 4096;
    }
    sniff_all<<<9, 256, 0, stream>>>(sa, modes);
    mpack<<<2048, 256, 0, stream>>>(mask, pmask);

    WtArgs wa;
    wa.W[0] = w_qs; wa.Wt[0] = Wtq; wa.slot[0] = 4;
    wa.W[1] = w_ks; wa.Wt[1] = Wtk; wa.slot[1] = 5;
    wa.W[2] = w_vs; wa.Wt[2] = Wtv; wa.slot[2] = 6;
    wtrans3<<<dim3(16, 16, 3), 256, 0, stream>>>(wa, modes);

    dim3 gproj(8, 64), gtr(16, 16);

    aconv<<<2048, 256, 0, stream>>>(query, Abuf, modes, 0);
    proj_mfma<<<gproj, 256, 0, stream>>>(Abuf, Wtq, Qw, 0, 0.125f);

    aconv<<<2048, 256, 0, stream>>>(key_i, Abuf, modes, 1);
    proj_mfma<<<gproj, 256, 0, stream>>>(Abuf, Wtk, Kw, 0, 1.0f);

    aconv<<<2048, 256, 0, stream>>>(value, Abuf, modes, 2);
    proj_mfma<<<gproj, 256, 0, stream>>>(Abuf, Wtv, Vw, 1, 1.0f);

    attn_mfma<<<dim3(32, 64), 256, 0, stream>>>(Qw, Kw, Vw, pmask, Xw);

    wtrans<<<gtr, 256, 0, stream>>>(w_out, Wt2, modes, 7);
    oproj_mfma<<<gproj, 256, 0, stream>>>(Xw, Wt2, query, out, modes);
    ln_k<<<2048, 256, 0, stream>>>(out, ln_g, ln_b, modes);
}